// Round 1
// baseline (664.626 us; speedup 1.0000x reference)
//
#include <hip/hip_runtime.h>

#define N_ROWS 100000
#define KNB 16
#define XN 128
#define XE 64
#define XO 128
#define KA 320            // 128 (x) + 128 (xnj) + 64 (xej)
#define AP 328            // padded A-row in bf16 elems (328*2B=656B -> 2-way LDS aliasing max)
#define MT 16             // rows per tile; 100000 % 16 == 0 -> no bounds checks
#define NTILES (N_ROWS / MT)
#define GRID_MAIN 2048

typedef __attribute__((ext_vector_type(8))) short bf16x8_t;   // 8 bf16 = 4 VGPRs
typedef __attribute__((ext_vector_type(4))) float f32x4_t;

__device__ __forceinline__ short f2bf(float f) {
  union { float f; unsigned u; } v; v.f = f;
  unsigned r = v.u + 0x7fffu + ((v.u >> 16) & 1u);   // RNE; inputs are finite
  return (short)(r >> 16);
}

// ij is declared int64 in the reference but the harness may hand us int32.
// int64 little-endian: odd 32-bit words are hi-words of small nonneg indices -> all 0.
// int32: odd words are random indices in [0,100000) -> P(all 16 zero) ~ 1e-80.
__global__ void detect_idx_kernel(const int* __restrict__ ij32, int* __restrict__ flag) {
  if (threadIdx.x == 0 && blockIdx.x == 0) {
    int all0 = 1;
    for (int i = 0; i < 16; ++i) all0 &= (ij32[2 * i + 1] == 0) ? 1 : 0;
    *flag = all0;   // 1 => int64 layout, 0 => int32 layout
  }
}

__global__ __launch_bounds__(256, 3) void conv_fused_kernel(
    const float* __restrict__ x, const float* __restrict__ e,
    const int* __restrict__ ij32,
    const float* __restrict__ Wc, const float* __restrict__ Wn,
    const float* __restrict__ We,
    const int* __restrict__ flag, float* __restrict__ out)
{
  __shared__ short As[MT][AP];     // A-tile: [x | xnj | xej] as bf16
  __shared__ int nhs[MT * KNB];    // gather indices for this tile

  const int tid  = threadIdx.x;
  const int wave = tid >> 6;
  const int lane = tid & 63;
  const int quad = lane >> 4;
  const int l16  = lane & 15;
  const int r16  = tid >> 4;       // row within tile (0..15)
  const int s16  = tid & 15;       // column-group within row

  const int shift = (*flag) ? 2 : 1;   // int32-index position = (n*K+k) << shift

  // ---- B fragments in registers: wave w owns output cols [32w, 32w+32) as two 16-col tiles.
  // B[k][j] = W_all[j][k]; lane l holds (k = ks*32 + quad*8 + 0..7, j = colbase + l16).
  bf16x8_t bfrag[2][10];
  #pragma unroll
  for (int t = 0; t < 2; ++t) {
    const int col = wave * 32 + t * 16 + l16;
    #pragma unroll
    for (int ks = 0; ks < 10; ++ks) {
      const int k = ks * 32 + quad * 8;     // never crosses the 128/256 boundaries
      const float* src;
      if (k < 128)      src = Wc + col * XN + k;
      else if (k < 256) src = Wn + col * XN + (k - 128);
      else              src = We + col * XE + (k - 256);
      float4 a = *(const float4*)src;
      float4 b = *(const float4*)(src + 4);
      bf16x8_t f;
      f[0] = f2bf(a.x); f[1] = f2bf(a.y); f[2] = f2bf(a.z); f[3] = f2bf(a.w);
      f[4] = f2bf(b.x); f[5] = f2bf(b.y); f[6] = f2bf(b.z); f[7] = f2bf(b.w);
      bfrag[t][ks] = f;
    }
  }

  for (int tile = blockIdx.x; tile < NTILES; tile += gridDim.x) {
    const int r0 = tile * MT;
    __syncthreads();   // protect As/nhs from previous iteration's readers

    // stage gather indices (1 per thread)
    nhs[tid] = ij32[((r0 + r16) * KNB + s16) << shift];

    // x part -> As[:, 0:128]
    {
      const float* p = x + (r0 + r16) * XN + s16 * 8;
      float4 a = *(const float4*)p;
      float4 b = *(const float4*)(p + 4);
      short* dst = &As[r16][s16 * 8];
      dst[0] = f2bf(a.x); dst[1] = f2bf(a.y); dst[2] = f2bf(a.z); dst[3] = f2bf(a.w);
      dst[4] = f2bf(b.x); dst[5] = f2bf(b.y); dst[6] = f2bf(b.z); dst[7] = f2bf(b.w);
    }
    // e mean -> As[:, 256:320]  (each thread owns 4 cols of one row)
    {
      const float* p = e + (r0 + r16) * (KNB * XE) + s16 * 4;
      float sx = 0.f, sy = 0.f, sz = 0.f, sw = 0.f;
      #pragma unroll 4
      for (int k = 0; k < KNB; ++k) {
        float4 v = *(const float4*)(p + k * XE);
        sx += v.x; sy += v.y; sz += v.z; sw += v.w;
      }
      short* dst = &As[r16][256 + s16 * 4];
      dst[0] = f2bf(sx * 0.0625f); dst[1] = f2bf(sy * 0.0625f);
      dst[2] = f2bf(sz * 0.0625f); dst[3] = f2bf(sw * 0.0625f);
    }
    __syncthreads();   // nhs ready
    // gather mean -> As[:, 128:256]  (each thread owns 8 cols of one row)
    {
      float s0=0,s1=0,s2=0,s3=0,s4=0,s5=0,s6=0,s7=0;
      #pragma unroll 4
      for (int k = 0; k < KNB; ++k) {
        int idx = nhs[r16 * KNB + k];
        idx = idx < 0 ? 0 : (idx >= N_ROWS ? N_ROWS - 1 : idx);   // safety clamp
        const float* p = x + idx * XN + s16 * 8;
        float4 a = *(const float4*)p;
        float4 b = *(const float4*)(p + 4);
        s0 += a.x; s1 += a.y; s2 += a.z; s3 += a.w;
        s4 += b.x; s5 += b.y; s6 += b.z; s7 += b.w;
      }
      short* dst = &As[r16][128 + s16 * 8];
      dst[0] = f2bf(s0 * 0.0625f); dst[1] = f2bf(s1 * 0.0625f);
      dst[2] = f2bf(s2 * 0.0625f); dst[3] = f2bf(s3 * 0.0625f);
      dst[4] = f2bf(s4 * 0.0625f); dst[5] = f2bf(s5 * 0.0625f);
      dst[6] = f2bf(s6 * 0.0625f); dst[7] = f2bf(s7 * 0.0625f);
    }
    __syncthreads();   // A-tile complete

    // ---- MFMA: 16 rows x 32 cols per wave, K=320 in 10 steps
    f32x4_t acc0 = {0.f, 0.f, 0.f, 0.f};
    f32x4_t acc1 = {0.f, 0.f, 0.f, 0.f};
    #pragma unroll
    for (int ks = 0; ks < 10; ++ks) {
      bf16x8_t af = *(const bf16x8_t*)(&As[l16][ks * 32 + quad * 8]);  // A[m=l16][k=quad*8+j]
      acc0 = __builtin_amdgcn_mfma_f32_16x16x32_bf16(af, bfrag[0][ks], acc0, 0, 0, 0);
      acc1 = __builtin_amdgcn_mfma_f32_16x16x32_bf16(af, bfrag[1][ks], acc1, 0, 0, 0);
    }

    // epilogue: C/D layout col = lane&15, row = quad*4 + reg
    const int colb = wave * 32 + l16;
    #pragma unroll
    for (int i = 0; i < 4; ++i) {
      const int row = r0 + quad * 4 + i;
      out[row * XO + colb]      = fmaxf(acc0[i], 0.f);
      out[row * XO + colb + 16] = fmaxf(acc1[i], 0.f);
    }
  }
}

extern "C" void kernel_launch(void* const* d_in, const int* in_sizes, int n_in,
                              void* d_out, int out_size, void* d_ws, size_t ws_size,
                              hipStream_t stream) {
  const float* x  = (const float*)d_in[0];
  const float* e  = (const float*)d_in[1];
  const int* ij32 = (const int*)d_in[2];
  const float* Wc = (const float*)d_in[3];
  const float* Wn = (const float*)d_in[4];
  const float* We = (const float*)d_in[5];
  float* out = (float*)d_out;
  int* flag = (int*)d_ws;

  detect_idx_kernel<<<1, 64, 0, stream>>>(ij32, flag);
  conv_fused_kernel<<<GRID_MAIN, 256, 0, stream>>>(x, e, ij32, Wc, Wn, We, flag, out);
}